// Round 5
// baseline (543.412 us; speedup 1.0000x reference)
//
#include <hip/hip_runtime.h>
#include <math.h>

#define DIMC 1024
#define BB   8
#define LL   2048
#define ACTC 256
#define HIDC 256
#define EPSV 1e-6f
#define MROWS (BB * LL)   // 16384
#define NCHUNK 32
#define LC     64         // LL / NCHUNK

typedef __bf16 bf16x8 __attribute__((ext_vector_type(8)));
typedef float  f32x4  __attribute__((ext_vector_type(4)));

__device__ __forceinline__ unsigned short f2bf(float f) {
    union { float f; unsigned int u; } v; v.f = f;
    unsigned int u = v.u + 0x7fffu + ((v.u >> 16) & 1u);
    return (unsigned short)(u >> 16);
}
__device__ __forceinline__ float bf2f(unsigned short s) {
    union { float f; unsigned int u; } v; v.u = ((unsigned int)s) << 16;
    return v.f;
}
// inf-safe fast sigmoid/tanh on native v_exp_f32
__device__ __forceinline__ float fast_sigmoid(float x) {
    return 1.0f / (1.0f + __expf(-x));
}
__device__ __forceinline__ float fast_tanh(float x) {
    float ax = fabsf(x);
    float t = 1.0f - 2.0f / (__expf(2.0f * ax) + 1.0f);  // exp(inf)->inf -> t=1
    return copysignf(t, x);
}

// ---------------- weight convert: all 5 weights in one launch ----------------
__global__ void k_convert5(const float* __restrict__ s0, const float* __restrict__ s1,
                           const float* __restrict__ s2, const float* __restrict__ s3,
                           const float* __restrict__ s4,
                           unsigned short* __restrict__ d0, unsigned short* __restrict__ d1,
                           unsigned short* __restrict__ d2, unsigned short* __restrict__ d3,
                           unsigned short* __restrict__ d4) {
    int i = blockIdx.x * blockDim.x + threadIdx.x;  // total 3670016
    if (i < 1048576)            d0[i]           = f2bf(s0[i]);
    else if (i < 2097152)       d1[i - 1048576] = f2bf(s1[i - 1048576]);
    else if (i < 3145728)       d2[i - 2097152] = f2bf(s2[i - 2097152]);
    else if (i < 3407872)       d3[i - 3145728] = f2bf(s3[i - 3145728]);
    else if (i < 3670016)       d4[i - 3407872] = f2bf(s4[i - 3407872]);
}

// ---------------- RMSNorm: one block per row, bf16 out ----------------
__global__ __launch_bounds__(256) void k_rmsnorm(const float* __restrict__ x,
                                                 const float* __restrict__ w,
                                                 unsigned short* __restrict__ xnb) {
    int m = blockIdx.x;
    int t = threadIdx.x;
    float4 v = ((const float4*)(x + (size_t)m * DIMC))[t];
    float ss = v.x*v.x + v.y*v.y + v.z*v.z + v.w*v.w;
#pragma unroll
    for (int off = 32; off > 0; off >>= 1) ss += __shfl_down(ss, off, 64);
    __shared__ float sred[4];
    if ((t & 63) == 0) sred[t >> 6] = ss;
    __syncthreads();
    float tot = sred[0] + sred[1] + sred[2] + sred[3];
    float rinv = 1.0f / sqrtf(tot * (1.0f / DIMC) + EPSV);
    float4 wv = ((const float4*)w)[t];
    uint2 o;
    o.x = (unsigned)f2bf(wv.x * v.x * rinv) | ((unsigned)f2bf(wv.y * v.y * rinv) << 16);
    o.y = (unsigned)f2bf(wv.z * v.z * rinv) | ((unsigned)f2bf(wv.w * v.w * rinv) << 16);
    ((uint2*)(xnb + (size_t)m * DIMC))[t] = o;
}

// ---------------- depthwise conv K=5, zero-pad, bf16 in/out ----------------
__global__ __launch_bounds__(256) void k_dwconv(const unsigned short* __restrict__ xnb,
                                                const float* __restrict__ dww,
                                                const float* __restrict__ dwb,
                                                unsigned short* __restrict__ xc) {
    int m = blockIdx.x;          // b*LL + l
    int l = m & (LL - 1);
    int t = threadIdx.x;         // channel group of 4
    int c0 = t * 4;
    float wgt[4][5];
#pragma unroll
    for (int j = 0; j < 4; ++j)
#pragma unroll
        for (int k = 0; k < 5; ++k) wgt[j][k] = dww[(c0 + j) * 5 + k];
    float4 bv = ((const float4*)dwb)[t];
    float acc[4] = {bv.x, bv.y, bv.z, bv.w};
#pragma unroll
    for (int k = 0; k < 5; ++k) {
        int ll = l + k - 2;
        if (ll < 0 || ll >= LL) continue;
        uint2 rv = ((const uint2*)(xnb + (size_t)(m + k - 2) * DIMC))[t];
        acc[0] += bf2f((unsigned short)(rv.x & 0xffff)) * wgt[0][k];
        acc[1] += bf2f((unsigned short)(rv.x >> 16))    * wgt[1][k];
        acc[2] += bf2f((unsigned short)(rv.y & 0xffff)) * wgt[2][k];
        acc[3] += bf2f((unsigned short)(rv.y >> 16))    * wgt[3][k];
    }
    uint2 o;
    o.x = (unsigned)f2bf(acc[0]) | ((unsigned)f2bf(acc[1]) << 16);
    o.y = (unsigned)f2bf(acc[2]) | ((unsigned)f2bf(acc[3]) << 16);
    ((uint2*)(xc + (size_t)m * DIMC))[t] = o;
}

// ---------------- chunked parallel scan ----------------
__global__ __launch_bounds__(256) void k_scan_a(const unsigned short* __restrict__ xnb,
                                                const float* __restrict__ alpha,
                                                const float* __restrict__ beta,
                                                float* __restrict__ F) {
    int blk = blockIdx.x;        // b*NCHUNK + k
    int b = blk >> 5, k = blk & (NCHUNK - 1);
    int c = threadIdx.x;
    float a = alpha[c], bt = beta[c];
    const unsigned short* p = xnb + ((size_t)(b * LL + k * LC)) * DIMC + c;
    float h = 0.0f;
    for (int l = 0; l < LC; ++l) h = a * h + bt * bf2f(p[(size_t)l * DIMC]);
    F[(size_t)blk * ACTC + c] = h;
}
__global__ __launch_bounds__(256) void k_scan_b(const float* __restrict__ alpha,
                                                const float* __restrict__ F,
                                                float* __restrict__ Cv) {
    int b = blockIdx.x;
    int c = threadIdx.x;
    float a = alpha[c];
    float aL = a;
#pragma unroll
    for (int i = 0; i < 6; ++i) aL *= aL;   // a^64
    float T = 0.0f;
    for (int k = 0; k < NCHUNK; ++k) {
        size_t idx = ((size_t)b * NCHUNK + k) * ACTC + c;
        Cv[idx] = T;
        T = F[idx] + aL * T;
    }
}
__global__ __launch_bounds__(256) void k_scan_c(const unsigned short* __restrict__ xnb,
                                                const float* __restrict__ alpha,
                                                const float* __restrict__ beta,
                                                const float* __restrict__ Cv,
                                                unsigned short* __restrict__ hs) {
    int blk = blockIdx.x;
    int b = blk >> 5, k = blk & (NCHUNK - 1);
    int c = threadIdx.x;
    float a = alpha[c], bt = beta[c];
    const unsigned short* p = xnb + ((size_t)(b * LL + k * LC)) * DIMC + c;
    unsigned short*       q = hs  + ((size_t)(b * LL + k * LC)) * ACTC + c;
    float h = Cv[(size_t)blk * ACTC + c];
    for (int l = 0; l < LC; ++l) {
        h = a * h + bt * bf2f(p[(size_t)l * DIMC]);
        q[(size_t)l * ACTC] = f2bf(h);
    }
}

// ---------------- MFMA GEMM, C = A(MxK) * B^T(NxK), fused epilogues ----------------
// XOR-swizzled LDS: global k-group (kg^(row&7)) stored at linear slot kg; reads
// fetch slot cg^(row&7). Kills the 16-way bank conflict of the 128B-stride layout.
#define TM 128
#define TN 128
#define BK 64

#define GLOAD_LDS(gp, lp) \
    __builtin_amdgcn_global_load_lds((const __attribute__((address_space(1))) unsigned int*)(gp), \
                                     (__attribute__((address_space(3))) unsigned int*)(lp), 16, 0, 0)

template<int MODE>
__global__ __launch_bounds__(256, (MODE == 1) ? 3 : 4) void k_gemm(
        const unsigned short* __restrict__ A,
        const unsigned short* __restrict__ B0,
        const unsigned short* __restrict__ B1,
        const float* __restrict__ bias0,
        const float* __restrict__ bias1,
        const unsigned short* __restrict__ add0,
        const unsigned short* __restrict__ add1,
        const float* __restrict__ addf,
        float* __restrict__ outf,
        unsigned short* __restrict__ outb,
        int M, int N, int K)
{
    constexpr int LDSB = (MODE == 1) ? 49152 : 32768;
    __shared__ __align__(16) char lds[LDSB];
    unsigned short* sA  = (unsigned short*)lds;
    unsigned short* sB0 = (unsigned short*)(lds + 16384);
    unsigned short* sB1 = (unsigned short*)(lds + 32768);

    // XCD-aware remap: bid&7 selects M-partition (XCD proxy), column varies
    // fastest within an XCD so the A-tile stays hot in that XCD's L2.
    int nx = gridDim.x;
    int bid = blockIdx.y * nx + blockIdx.x;
    int xcd = bid & 7, s = bid >> 3;
    int colt = s % nx, rowgrp = s / nx;
    int m0 = (rowgrp * 8 + xcd) * TM;
    int n0 = colt * TN;

    int t = threadIdx.x;
    int w = t >> 6, lane = t & 63;
    int wm = (w >> 1) * 64, wn = (w & 1) * 64;
    int quad = lane >> 4, lm = lane & 15;
    int lm7 = lm & 7;

    f32x4 zero = {0.f, 0.f, 0.f, 0.f};
    f32x4 acc0[4][4];
    f32x4 acc1[(MODE == 1) ? 4 : 1][(MODE == 1) ? 4 : 1];
#pragma unroll
    for (int i = 0; i < 4; ++i)
#pragma unroll
        for (int j = 0; j < 4; ++j) acc0[i][j] = zero;
    if constexpr (MODE == 1) {
#pragma unroll
        for (int i = 0; i < 4; ++i)
#pragma unroll
            for (int j = 0; j < 4; ++j) acc1[i][j] = zero;
    }

    for (int k0 = 0; k0 < K; k0 += BK) {
        __syncthreads();
#pragma unroll
        for (int c = 0; c < 4; ++c) {
            int i = t + c * 256;
            int r = i >> 3;
            int sc = ((i & 7) ^ (r & 7)) << 3;   // swizzled source k-group
            GLOAD_LDS(A  + (size_t)(m0 + r) * K + k0 + sc, sA  + i * 8);
            GLOAD_LDS(B0 + (size_t)(n0 + r) * K + k0 + sc, sB0 + i * 8);
            if constexpr (MODE == 1)
                GLOAD_LDS(B1 + (size_t)(n0 + r) * K + k0 + sc, sB1 + i * 8);
        }
        __syncthreads();

#pragma unroll
        for (int ks = 0; ks < BK; ks += 32) {
            int cgb = ks >> 3;   // 0 or 4
            bf16x8 af[4], b0f[4];
#pragma unroll
            for (int i = 0; i < 4; ++i) {
                int sg = ((cgb + quad) ^ lm7) << 3;
                af[i]  = *(const bf16x8*)(sA  + (wm + i * 16 + lm) * BK + sg);
                b0f[i] = *(const bf16x8*)(sB0 + (wn + i * 16 + lm) * BK + sg);
            }
            if constexpr (MODE == 1) {
                bf16x8 b1f[4];
#pragma unroll
                for (int i = 0; i < 4; ++i)
                    b1f[i] = *(const bf16x8*)(sB1 + (wn + i * 16 + lm) * BK + (((cgb + quad) ^ lm7) << 3));
#pragma unroll
                for (int mi = 0; mi < 4; ++mi)
#pragma unroll
                    for (int ni = 0; ni < 4; ++ni) {
                        acc0[mi][ni] = __builtin_amdgcn_mfma_f32_16x16x32_bf16(af[mi], b0f[ni], acc0[mi][ni], 0, 0, 0);
                        acc1[mi][ni] = __builtin_amdgcn_mfma_f32_16x16x32_bf16(af[mi], b1f[ni], acc1[mi][ni], 0, 0, 0);
                    }
            } else {
#pragma unroll
                for (int mi = 0; mi < 4; ++mi)
#pragma unroll
                    for (int ni = 0; ni < 4; ++ni)
                        acc0[mi][ni] = __builtin_amdgcn_mfma_f32_16x16x32_bf16(af[mi], b0f[ni], acc0[mi][ni], 0, 0, 0);
            }
        }
    }

    // -------- epilogue: compute in acc layout -> pack to LDS -> coalesced store --------
    __syncthreads();
    if constexpr (MODE == 3) {
        // fp32 output in two 64-row chunks to stay within 32 KB LDS
        float* sO = (float*)lds;
#pragma unroll
        for (int half = 0; half < 2; ++half) {
            if (wm == half * 64) {
#pragma unroll
                for (int mi = 0; mi < 4; ++mi) {
#pragma unroll
                    for (int ni = 0; ni < 4; ++ni) {
                        int nl = wn + ni * 16 + lm;
                        int n  = n0 + nl;
                        float bn = bias0[n];
#pragma unroll
                        for (int j = 0; j < 4; ++j) {
                            int mloc = mi * 16 + quad * 4 + j;   // 0..63
                            size_t idx = (size_t)(m0 + wm + mloc) * N + n;
                            sO[mloc * TN + nl] = bf2f(add0[idx]) + acc0[mi][ni][j] + bn + addf[idx];
                        }
                    }
                }
            }
            __syncthreads();
#pragma unroll
            for (int c = 0; c < 8; ++c) {
                int i = t + c * 256;
                int r = i >> 5, c4 = (i & 31) << 2;
                *(float4*)(outf + (size_t)(m0 + half * 64 + r) * N + n0 + c4) = *(float4*)(sO + r * TN + c4);
            }
            __syncthreads();
        }
    } else {
        unsigned short* sO = (unsigned short*)lds;
#pragma unroll
        for (int mi = 0; mi < 4; ++mi) {
#pragma unroll
            for (int ni = 0; ni < 4; ++ni) {
                int nl = wn + ni * 16 + lm;
                int n  = n0 + nl;
                float bn = bias0[n];
                float bn1 = (MODE == 1) ? bias1[n] : 0.0f;
#pragma unroll
                for (int j = 0; j < 4; ++j) {
                    int ml = wm + mi * 16 + quad * 4 + j;
                    int m  = m0 + ml;
                    float v = acc0[mi][ni][j];
                    float r;
                    if constexpr (MODE == 0) {
                        r = v + bn + ((n < ACTC) ? bf2f(add0[(size_t)m * ACTC + n])
                                                 : bf2f(add1[(size_t)m * DIMC + n]));
                    } else if constexpr (MODE == 1) {
                        float u1 = v + bn;
                        float u2 = acc1[mi][ni][j] + bn1;
                        r = bf2f(add0[(size_t)m * N + n]) + fast_sigmoid(u1) * fast_tanh(u2);
                    } else { // MODE 2
                        float u = v + bn;
                        r = 0.5f * u * (1.0f + erff(u * 0.70710678118654752f));
                    }
                    sO[ml * TN + nl] = f2bf(r);
                }
            }
        }
        __syncthreads();
#pragma unroll
        for (int c = 0; c < 8; ++c) {
            int i = t + c * 256;
            int r = i >> 4, c8 = (i & 15) << 3;
            *(uint4*)(outb + (size_t)(m0 + r) * N + n0 + c8) = *(uint4*)(sO + r * TN + c8);
        }
    }
}

extern "C" void kernel_launch(void* const* d_in, const int* in_sizes, int n_in,
                              void* d_out, int out_size, void* d_ws, size_t ws_size,
                              hipStream_t stream) {
    (void)in_sizes; (void)n_in; (void)out_size; (void)ws_size;
    const float* x      = (const float*)d_in[0];
    const float* norm_w = (const float*)d_in[1];
    const float* dw_w   = (const float*)d_in[2];
    const float* dw_b   = (const float*)d_in[3];
    const float* pw_w   = (const float*)d_in[4];
    const float* pw_b   = (const float*)d_in[5];
    const float* alpha  = (const float*)d_in[6];
    const float* beta   = (const float*)d_in[7];
    const float* W1_w   = (const float*)d_in[8];
    const float* W1_b   = (const float*)d_in[9];
    const float* W2_w   = (const float*)d_in[10];
    const float* W2_b   = (const float*)d_in[11];
    const float* down_w = (const float*)d_in[12];
    const float* down_b = (const float*)d_in[13];
    const float* up_w   = (const float*)d_in[14];
    const float* up_b   = (const float*)d_in[15];

    char* ws = (char*)d_ws;
    unsigned short* xnb  = (unsigned short*)(ws);
    unsigned short* xc   = (unsigned short*)(ws + 33554432ull);
    unsigned short* hs   = (unsigned short*)(ws + 67108864ull);
    unsigned short* y1b  = (unsigned short*)(ws + 75497472ull);
    unsigned short* y2b  = (unsigned short*)(ws + 109051904ull);
    unsigned short* gact = (unsigned short*)(ws + 142606336ull);
    unsigned short* wpw  = (unsigned short*)(ws + 150994944ull);
    unsigned short* w1b  = wpw + 1048576;
    unsigned short* w2b  = w1b + 1048576;
    unsigned short* wdn  = w2b + 1048576;
    unsigned short* wup  = wdn + 262144;
    float*          Fb   = (float*)(ws + 159383552ull);
    float*          Cb   = (float*)(ws + 159383552ull + 262144ull);

    k_convert5<<<14336, 256, 0, stream>>>(pw_w, W1_w, W2_w, down_w, up_w,
                                          wpw, w1b, w2b, wdn, wup);

    k_rmsnorm<<<MROWS, 256, 0, stream>>>(x, norm_w, xnb);
    k_dwconv <<<MROWS, 256, 0, stream>>>(xnb, dw_w, dw_b, xc);

    k_scan_a<<<BB * NCHUNK, ACTC, 0, stream>>>(xnb, alpha, beta, Fb);
    k_scan_b<<<BB, ACTC, 0, stream>>>(alpha, Fb, Cb);
    k_scan_c<<<BB * NCHUNK, ACTC, 0, stream>>>(xnb, alpha, beta, Cb, hs);

    dim3 g1(DIMC / TN, MROWS / TM);
    dim3 g2(HIDC / TN, MROWS / TM);
    k_gemm<0><<<g1, 256, 0, stream>>>(xc, wpw, nullptr, pw_b, nullptr, hs, xnb, nullptr, nullptr, y1b, MROWS, DIMC, DIMC);
    k_gemm<1><<<g1, 256, 0, stream>>>(y1b, w1b, w2b, W1_b, W2_b, y1b, nullptr, nullptr, nullptr, y2b, MROWS, DIMC, DIMC);
    k_gemm<2><<<g2, 256, 0, stream>>>(y2b, wdn, nullptr, down_b, nullptr, nullptr, nullptr, nullptr, nullptr, gact, MROWS, HIDC, DIMC);
    k_gemm<3><<<g1, 256, 0, stream>>>(gact, wup, nullptr, up_b, nullptr, y2b, nullptr, x, (float*)d_out, nullptr, MROWS, DIMC, HIDC);
}

// Round 6
// 396.893 us; speedup vs baseline: 1.3692x; 1.3692x over previous
//
#include <hip/hip_runtime.h>
#include <math.h>

#define DIMC 1024
#define BB   8
#define LL   2048
#define ACTC 256
#define HIDC 256
#define EPSV 1e-6f
#define MROWS (BB * LL)   // 16384
#define NCHUNK 32
#define LC     64         // LL / NCHUNK

typedef __bf16 bf16x8 __attribute__((ext_vector_type(8)));
typedef float  f32x4  __attribute__((ext_vector_type(4)));

__device__ __forceinline__ unsigned short f2bf(float f) {
    union { float f; unsigned int u; } v; v.f = f;
    unsigned int u = v.u + 0x7fffu + ((v.u >> 16) & 1u);
    return (unsigned short)(u >> 16);
}
__device__ __forceinline__ float bf2f(unsigned short s) {
    union { float f; unsigned int u; } v; v.u = ((unsigned int)s) << 16;
    return v.f;
}
// inf-safe fast sigmoid/tanh on native v_exp_f32
__device__ __forceinline__ float fast_sigmoid(float x) {
    return 1.0f / (1.0f + __expf(-x));
}
__device__ __forceinline__ float fast_tanh(float x) {
    float ax = fabsf(x);
    float t = 1.0f - 2.0f / (__expf(2.0f * ax) + 1.0f);  // exp(inf)->inf -> t=1
    return copysignf(t, x);
}

// ---------------- weight convert: all 5 weights in one launch ----------------
__global__ void k_convert5(const float* __restrict__ s0, const float* __restrict__ s1,
                           const float* __restrict__ s2, const float* __restrict__ s3,
                           const float* __restrict__ s4,
                           unsigned short* __restrict__ d0, unsigned short* __restrict__ d1,
                           unsigned short* __restrict__ d2, unsigned short* __restrict__ d3,
                           unsigned short* __restrict__ d4) {
    int i = blockIdx.x * blockDim.x + threadIdx.x;  // total 3670016
    if (i < 1048576)            d0[i]           = f2bf(s0[i]);
    else if (i < 2097152)       d1[i - 1048576] = f2bf(s1[i - 1048576]);
    else if (i < 3145728)       d2[i - 2097152] = f2bf(s2[i - 2097152]);
    else if (i < 3407872)       d3[i - 3145728] = f2bf(s3[i - 3145728]);
    else if (i < 3670016)       d4[i - 3407872] = f2bf(s4[i - 3407872]);
}

// ---------------- RMSNorm: one block per row, bf16 out ----------------
__global__ __launch_bounds__(256) void k_rmsnorm(const float* __restrict__ x,
                                                 const float* __restrict__ w,
                                                 unsigned short* __restrict__ xnb) {
    int m = blockIdx.x;
    int t = threadIdx.x;
    float4 v = ((const float4*)(x + (size_t)m * DIMC))[t];
    float ss = v.x*v.x + v.y*v.y + v.z*v.z + v.w*v.w;
#pragma unroll
    for (int off = 32; off > 0; off >>= 1) ss += __shfl_down(ss, off, 64);
    __shared__ float sred[4];
    if ((t & 63) == 0) sred[t >> 6] = ss;
    __syncthreads();
    float tot = sred[0] + sred[1] + sred[2] + sred[3];
    float rinv = 1.0f / sqrtf(tot * (1.0f / DIMC) + EPSV);
    float4 wv = ((const float4*)w)[t];
    uint2 o;
    o.x = (unsigned)f2bf(wv.x * v.x * rinv) | ((unsigned)f2bf(wv.y * v.y * rinv) << 16);
    o.y = (unsigned)f2bf(wv.z * v.z * rinv) | ((unsigned)f2bf(wv.w * v.w * rinv) << 16);
    ((uint2*)(xnb + (size_t)m * DIMC))[t] = o;
}

// ---------------- depthwise conv K=5, zero-pad, bf16 in/out ----------------
__global__ __launch_bounds__(256) void k_dwconv(const unsigned short* __restrict__ xnb,
                                                const float* __restrict__ dww,
                                                const float* __restrict__ dwb,
                                                unsigned short* __restrict__ xc) {
    int m = blockIdx.x;          // b*LL + l
    int l = m & (LL - 1);
    int t = threadIdx.x;         // channel group of 4
    int c0 = t * 4;
    float wgt[4][5];
#pragma unroll
    for (int j = 0; j < 4; ++j)
#pragma unroll
        for (int k = 0; k < 5; ++k) wgt[j][k] = dww[(c0 + j) * 5 + k];
    float4 bv = ((const float4*)dwb)[t];
    float acc[4] = {bv.x, bv.y, bv.z, bv.w};
#pragma unroll
    for (int k = 0; k < 5; ++k) {
        int ll = l + k - 2;
        if (ll < 0 || ll >= LL) continue;
        uint2 rv = ((const uint2*)(xnb + (size_t)(m + k - 2) * DIMC))[t];
        acc[0] += bf2f((unsigned short)(rv.x & 0xffff)) * wgt[0][k];
        acc[1] += bf2f((unsigned short)(rv.x >> 16))    * wgt[1][k];
        acc[2] += bf2f((unsigned short)(rv.y & 0xffff)) * wgt[2][k];
        acc[3] += bf2f((unsigned short)(rv.y >> 16))    * wgt[3][k];
    }
    uint2 o;
    o.x = (unsigned)f2bf(acc[0]) | ((unsigned)f2bf(acc[1]) << 16);
    o.y = (unsigned)f2bf(acc[2]) | ((unsigned)f2bf(acc[3]) << 16);
    ((uint2*)(xc + (size_t)m * DIMC))[t] = o;
}

// ---------------- chunked parallel scan ----------------
__global__ __launch_bounds__(256) void k_scan_a(const unsigned short* __restrict__ xnb,
                                                const float* __restrict__ alpha,
                                                const float* __restrict__ beta,
                                                float* __restrict__ F) {
    int blk = blockIdx.x;        // b*NCHUNK + k
    int b = blk >> 5, k = blk & (NCHUNK - 1);
    int c = threadIdx.x;
    float a = alpha[c], bt = beta[c];
    const unsigned short* p = xnb + ((size_t)(b * LL + k * LC)) * DIMC + c;
    float h = 0.0f;
    for (int l = 0; l < LC; ++l) h = a * h + bt * bf2f(p[(size_t)l * DIMC]);
    F[(size_t)blk * ACTC + c] = h;
}
__global__ __launch_bounds__(256) void k_scan_b(const float* __restrict__ alpha,
                                                const float* __restrict__ F,
                                                float* __restrict__ Cv) {
    int b = blockIdx.x;
    int c = threadIdx.x;
    float a = alpha[c];
    float aL = a;
#pragma unroll
    for (int i = 0; i < 6; ++i) aL *= aL;   // a^64
    float T = 0.0f;
    for (int k = 0; k < NCHUNK; ++k) {
        size_t idx = ((size_t)b * NCHUNK + k) * ACTC + c;
        Cv[idx] = T;
        T = F[idx] + aL * T;
    }
}
__global__ __launch_bounds__(256) void k_scan_c(const unsigned short* __restrict__ xnb,
                                                const float* __restrict__ alpha,
                                                const float* __restrict__ beta,
                                                const float* __restrict__ Cv,
                                                unsigned short* __restrict__ hs) {
    int blk = blockIdx.x;
    int b = blk >> 5, k = blk & (NCHUNK - 1);
    int c = threadIdx.x;
    float a = alpha[c], bt = beta[c];
    const unsigned short* p = xnb + ((size_t)(b * LL + k * LC)) * DIMC + c;
    unsigned short*       q = hs  + ((size_t)(b * LL + k * LC)) * ACTC + c;
    float h = Cv[(size_t)blk * ACTC + c];
    for (int l = 0; l < LC; ++l) {
        h = a * h + bt * bf2f(p[(size_t)l * DIMC]);
        q[(size_t)l * ACTC] = f2bf(h);
    }
}

// ---------------- MFMA GEMM, C = A(MxK) * B^T(NxK), fused epilogues ----------------
// XOR-swizzled LDS: global k-group (kg^(row&7)) stored at linear slot kg; reads
// fetch slot cg^(row&7). Kills the 16-way bank conflict of the 128B-stride layout.
// NOTE: MODE1 must stay at launch_bounds(256,2) — (256,3) caps VGPRs at ~85 and
// spills the 2x 4x4 f32x4 accumulators to scratch (R5: WRITE_SIZE 32->121MB, 2.2x slower).
#define TM 128
#define TN 128
#define BK 64

#define GLOAD_LDS(gp, lp) \
    __builtin_amdgcn_global_load_lds((const __attribute__((address_space(1))) unsigned int*)(gp), \
                                     (__attribute__((address_space(3))) unsigned int*)(lp), 16, 0, 0)

template<int MODE>
__global__ __launch_bounds__(256, (MODE == 1) ? 2 : 4) void k_gemm(
        const unsigned short* __restrict__ A,
        const unsigned short* __restrict__ B0,
        const unsigned short* __restrict__ B1,
        const float* __restrict__ bias0,
        const float* __restrict__ bias1,
        const unsigned short* __restrict__ add0,
        const unsigned short* __restrict__ add1,
        const float* __restrict__ addf,
        float* __restrict__ outf,
        unsigned short* __restrict__ outb,
        int M, int N, int K)
{
    constexpr int LDSB = (MODE == 1) ? 49152 : 32768;
    __shared__ __align__(16) char lds[LDSB];
    unsigned short* sA  = (unsigned short*)lds;
    unsigned short* sB0 = (unsigned short*)(lds + 16384);
    unsigned short* sB1 = (unsigned short*)(lds + 32768);

    // XCD-aware remap: bid&7 selects M-partition (XCD proxy), column varies
    // fastest within an XCD so the A-tile stays hot in that XCD's L2.
    int nx = gridDim.x;
    int bid = blockIdx.y * nx + blockIdx.x;
    int xcd = bid & 7, s = bid >> 3;
    int colt = s % nx, rowgrp = s / nx;
    int m0 = (rowgrp * 8 + xcd) * TM;
    int n0 = colt * TN;

    int t = threadIdx.x;
    int w = t >> 6, lane = t & 63;
    int wm = (w >> 1) * 64, wn = (w & 1) * 64;
    int quad = lane >> 4, lm = lane & 15;
    int lm7 = lm & 7;

    f32x4 zero = {0.f, 0.f, 0.f, 0.f};
    f32x4 acc0[4][4];
    f32x4 acc1[(MODE == 1) ? 4 : 1][(MODE == 1) ? 4 : 1];
#pragma unroll
    for (int i = 0; i < 4; ++i)
#pragma unroll
        for (int j = 0; j < 4; ++j) acc0[i][j] = zero;
    if constexpr (MODE == 1) {
#pragma unroll
        for (int i = 0; i < 4; ++i)
#pragma unroll
            for (int j = 0; j < 4; ++j) acc1[i][j] = zero;
    }

    for (int k0 = 0; k0 < K; k0 += BK) {
        __syncthreads();
#pragma unroll
        for (int c = 0; c < 4; ++c) {
            int i = t + c * 256;
            int r = i >> 3;
            int sc = ((i & 7) ^ (r & 7)) << 3;   // swizzled source k-group
            GLOAD_LDS(A  + (size_t)(m0 + r) * K + k0 + sc, sA  + i * 8);
            GLOAD_LDS(B0 + (size_t)(n0 + r) * K + k0 + sc, sB0 + i * 8);
            if constexpr (MODE == 1)
                GLOAD_LDS(B1 + (size_t)(n0 + r) * K + k0 + sc, sB1 + i * 8);
        }
        __syncthreads();

#pragma unroll
        for (int ks = 0; ks < BK; ks += 32) {
            int cgb = ks >> 3;   // 0 or 4
            bf16x8 af[4], b0f[4];
#pragma unroll
            for (int i = 0; i < 4; ++i) {
                int sg = ((cgb + quad) ^ lm7) << 3;
                af[i]  = *(const bf16x8*)(sA  + (wm + i * 16 + lm) * BK + sg);
                b0f[i] = *(const bf16x8*)(sB0 + (wn + i * 16 + lm) * BK + sg);
            }
            if constexpr (MODE == 1) {
                bf16x8 b1f[4];
#pragma unroll
                for (int i = 0; i < 4; ++i)
                    b1f[i] = *(const bf16x8*)(sB1 + (wn + i * 16 + lm) * BK + (((cgb + quad) ^ lm7) << 3));
#pragma unroll
                for (int mi = 0; mi < 4; ++mi)
#pragma unroll
                    for (int ni = 0; ni < 4; ++ni) {
                        acc0[mi][ni] = __builtin_amdgcn_mfma_f32_16x16x32_bf16(af[mi], b0f[ni], acc0[mi][ni], 0, 0, 0);
                        acc1[mi][ni] = __builtin_amdgcn_mfma_f32_16x16x32_bf16(af[mi], b1f[ni], acc1[mi][ni], 0, 0, 0);
                    }
            } else {
#pragma unroll
                for (int mi = 0; mi < 4; ++mi)
#pragma unroll
                    for (int ni = 0; ni < 4; ++ni)
                        acc0[mi][ni] = __builtin_amdgcn_mfma_f32_16x16x32_bf16(af[mi], b0f[ni], acc0[mi][ni], 0, 0, 0);
            }
        }
    }

    // -------- epilogue: compute in acc layout -> pack to LDS -> coalesced store --------
    __syncthreads();
    if constexpr (MODE == 3) {
        // fp32 output in two 64-row chunks to stay within 32 KB LDS
        float* sO = (float*)lds;
#pragma unroll
        for (int half = 0; half < 2; ++half) {
            if (wm == half * 64) {
#pragma unroll
                for (int mi = 0; mi < 4; ++mi) {
#pragma unroll
                    for (int ni = 0; ni < 4; ++ni) {
                        int nl = wn + ni * 16 + lm;
                        int n  = n0 + nl;
                        float bn = bias0[n];
#pragma unroll
                        for (int j = 0; j < 4; ++j) {
                            int mloc = mi * 16 + quad * 4 + j;   // 0..63
                            size_t idx = (size_t)(m0 + wm + mloc) * N + n;
                            sO[mloc * TN + nl] = bf2f(add0[idx]) + acc0[mi][ni][j] + bn + addf[idx];
                        }
                    }
                }
            }
            __syncthreads();
#pragma unroll
            for (int c = 0; c < 8; ++c) {
                int i = t + c * 256;
                int r = i >> 5, c4 = (i & 31) << 2;
                *(float4*)(outf + (size_t)(m0 + half * 64 + r) * N + n0 + c4) = *(float4*)(sO + r * TN + c4);
            }
            __syncthreads();
        }
    } else {
        unsigned short* sO = (unsigned short*)lds;
#pragma unroll
        for (int mi = 0; mi < 4; ++mi) {
#pragma unroll
            for (int ni = 0; ni < 4; ++ni) {
                int nl = wn + ni * 16 + lm;
                int n  = n0 + nl;
                float bn = bias0[n];
                float bn1 = (MODE == 1) ? bias1[n] : 0.0f;
#pragma unroll
                for (int j = 0; j < 4; ++j) {
                    int ml = wm + mi * 16 + quad * 4 + j;
                    int m  = m0 + ml;
                    float v = acc0[mi][ni][j];
                    float r;
                    if constexpr (MODE == 0) {
                        r = v + bn + ((n < ACTC) ? bf2f(add0[(size_t)m * ACTC + n])
                                                 : bf2f(add1[(size_t)m * DIMC + n]));
                    } else if constexpr (MODE == 1) {
                        float u1 = v + bn;
                        float u2 = acc1[mi][ni][j] + bn1;
                        r = bf2f(add0[(size_t)m * N + n]) + fast_sigmoid(u1) * fast_tanh(u2);
                    } else { // MODE 2
                        float u = v + bn;
                        r = 0.5f * u * (1.0f + erff(u * 0.70710678118654752f));
                    }
                    sO[ml * TN + nl] = f2bf(r);
                }
            }
        }
        __syncthreads();
#pragma unroll
        for (int c = 0; c < 8; ++c) {
            int i = t + c * 256;
            int r = i >> 4, c8 = (i & 15) << 3;
            *(uint4*)(outb + (size_t)(m0 + r) * N + n0 + c8) = *(uint4*)(sO + r * TN + c8);
        }
    }
}

extern "C" void kernel_launch(void* const* d_in, const int* in_sizes, int n_in,
                              void* d_out, int out_size, void* d_ws, size_t ws_size,
                              hipStream_t stream) {
    (void)in_sizes; (void)n_in; (void)out_size; (void)ws_size;
    const float* x      = (const float*)d_in[0];
    const float* norm_w = (const float*)d_in[1];
    const float* dw_w   = (const float*)d_in[2];
    const float* dw_b   = (const float*)d_in[3];
    const float* pw_w   = (const float*)d_in[4];
    const float* pw_b   = (const float*)d_in[5];
    const float* alpha  = (const float*)d_in[6];
    const float* beta   = (const float*)d_in[7];
    const float* W1_w   = (const float*)d_in[8];
    const float* W1_b   = (const float*)d_in[9];
    const float* W2_w   = (const float*)d_in[10];
    const float* W2_b   = (const float*)d_in[11];
    const float* down_w = (const float*)d_in[12];
    const float* down_b = (const float*)d_in[13];
    const float* up_w   = (const float*)d_in[14];
    const float* up_b   = (const float*)d_in[15];

    char* ws = (char*)d_ws;
    unsigned short* xnb  = (unsigned short*)(ws);
    unsigned short* xc   = (unsigned short*)(ws + 33554432ull);
    unsigned short* hs   = (unsigned short*)(ws + 67108864ull);
    unsigned short* y1b  = (unsigned short*)(ws + 75497472ull);
    unsigned short* y2b  = (unsigned short*)(ws + 109051904ull);
    unsigned short* gact = (unsigned short*)(ws + 142606336ull);
    unsigned short* wpw  = (unsigned short*)(ws + 150994944ull);
    unsigned short* w1b  = wpw + 1048576;
    unsigned short* w2b  = w1b + 1048576;
    unsigned short* wdn  = w2b + 1048576;
    unsigned short* wup  = wdn + 262144;
    float*          Fb   = (float*)(ws + 159383552ull);
    float*          Cb   = (float*)(ws + 159383552ull + 262144ull);

    k_convert5<<<14336, 256, 0, stream>>>(pw_w, W1_w, W2_w, down_w, up_w,
                                          wpw, w1b, w2b, wdn, wup);

    k_rmsnorm<<<MROWS, 256, 0, stream>>>(x, norm_w, xnb);
    k_dwconv <<<MROWS, 256, 0, stream>>>(xnb, dw_w, dw_b, xc);

    k_scan_a<<<BB * NCHUNK, ACTC, 0, stream>>>(xnb, alpha, beta, Fb);
    k_scan_b<<<BB, ACTC, 0, stream>>>(alpha, Fb, Cb);
    k_scan_c<<<BB * NCHUNK, ACTC, 0, stream>>>(xnb, alpha, beta, Cb, hs);

    dim3 g1(DIMC / TN, MROWS / TM);
    dim3 g2(HIDC / TN, MROWS / TM);
    k_gemm<0><<<g1, 256, 0, stream>>>(xc, wpw, nullptr, pw_b, nullptr, hs, xnb, nullptr, nullptr, y1b, MROWS, DIMC, DIMC);
    k_gemm<1><<<g1, 256, 0, stream>>>(y1b, w1b, w2b, W1_b, W2_b, y1b, nullptr, nullptr, nullptr, y2b, MROWS, DIMC, DIMC);
    k_gemm<2><<<g2, 256, 0, stream>>>(y2b, wdn, nullptr, down_b, nullptr, nullptr, nullptr, nullptr, nullptr, gact, MROWS, HIDC, DIMC);
    k_gemm<3><<<g1, 256, 0, stream>>>(gact, wup, nullptr, up_b, nullptr, y2b, nullptr, x, (float*)d_out, nullptr, MROWS, DIMC, HIDC);
}

// Round 7
// 388.872 us; speedup vs baseline: 1.3974x; 1.0206x over previous
//
#include <hip/hip_runtime.h>
#include <math.h>

#define DIMC 1024
#define BB   8
#define LL   2048
#define ACTC 256
#define HIDC 256
#define EPSV 1e-6f
#define MROWS (BB * LL)   // 16384
#define NCHUNK 32
#define LC     64         // LL / NCHUNK

typedef __bf16 bf16x8 __attribute__((ext_vector_type(8)));
typedef float  f32x4  __attribute__((ext_vector_type(4)));

__device__ __forceinline__ unsigned short f2bf(float f) {
    union { float f; unsigned int u; } v; v.f = f;
    unsigned int u = v.u + 0x7fffu + ((v.u >> 16) & 1u);
    return (unsigned short)(u >> 16);
}
__device__ __forceinline__ float bf2f(unsigned short s) {
    union { float f; unsigned int u; } v; v.u = ((unsigned int)s) << 16;
    return v.f;
}
// inf-safe fast sigmoid/tanh on native v_exp_f32
__device__ __forceinline__ float fast_sigmoid(float x) {
    return 1.0f / (1.0f + __expf(-x));
}
__device__ __forceinline__ float fast_tanh(float x) {
    float ax = fabsf(x);
    float t = 1.0f - 2.0f / (__expf(2.0f * ax) + 1.0f);  // exp(inf)->inf -> t=1
    return copysignf(t, x);
}

// ---------------- weight convert: all 5 weights in one launch ----------------
__global__ void k_convert5(const float* __restrict__ s0, const float* __restrict__ s1,
                           const float* __restrict__ s2, const float* __restrict__ s3,
                           const float* __restrict__ s4,
                           unsigned short* __restrict__ d0, unsigned short* __restrict__ d1,
                           unsigned short* __restrict__ d2, unsigned short* __restrict__ d3,
                           unsigned short* __restrict__ d4) {
    int i = blockIdx.x * blockDim.x + threadIdx.x;  // total 3670016
    if (i < 1048576)            d0[i]           = f2bf(s0[i]);
    else if (i < 2097152)       d1[i - 1048576] = f2bf(s1[i - 1048576]);
    else if (i < 3145728)       d2[i - 2097152] = f2bf(s2[i - 2097152]);
    else if (i < 3407872)       d3[i - 3145728] = f2bf(s3[i - 3145728]);
    else if (i < 3670016)       d4[i - 3407872] = f2bf(s4[i - 3407872]);
}

// ---------------- RMSNorm: one block per row, bf16 out ----------------
__global__ __launch_bounds__(256) void k_rmsnorm(const float* __restrict__ x,
                                                 const float* __restrict__ w,
                                                 unsigned short* __restrict__ xnb) {
    int m = blockIdx.x;
    int t = threadIdx.x;
    float4 v = ((const float4*)(x + (size_t)m * DIMC))[t];
    float ss = v.x*v.x + v.y*v.y + v.z*v.z + v.w*v.w;
#pragma unroll
    for (int off = 32; off > 0; off >>= 1) ss += __shfl_down(ss, off, 64);
    __shared__ float sred[4];
    if ((t & 63) == 0) sred[t >> 6] = ss;
    __syncthreads();
    float tot = sred[0] + sred[1] + sred[2] + sred[3];
    float rinv = 1.0f / sqrtf(tot * (1.0f / DIMC) + EPSV);
    float4 wv = ((const float4*)w)[t];
    uint2 o;
    o.x = (unsigned)f2bf(wv.x * v.x * rinv) | ((unsigned)f2bf(wv.y * v.y * rinv) << 16);
    o.y = (unsigned)f2bf(wv.z * v.z * rinv) | ((unsigned)f2bf(wv.w * v.w * rinv) << 16);
    ((uint2*)(xnb + (size_t)m * DIMC))[t] = o;
}

// ---------------- depthwise conv K=5, zero-pad, bf16 in/out ----------------
__global__ __launch_bounds__(256) void k_dwconv(const unsigned short* __restrict__ xnb,
                                                const float* __restrict__ dww,
                                                const float* __restrict__ dwb,
                                                unsigned short* __restrict__ xc) {
    int m = blockIdx.x;          // b*LL + l
    int l = m & (LL - 1);
    int t = threadIdx.x;         // channel group of 4
    int c0 = t * 4;
    float wgt[4][5];
#pragma unroll
    for (int j = 0; j < 4; ++j)
#pragma unroll
        for (int k = 0; k < 5; ++k) wgt[j][k] = dww[(c0 + j) * 5 + k];
    float4 bv = ((const float4*)dwb)[t];
    float acc[4] = {bv.x, bv.y, bv.z, bv.w};
#pragma unroll
    for (int k = 0; k < 5; ++k) {
        int ll = l + k - 2;
        if (ll < 0 || ll >= LL) continue;
        uint2 rv = ((const uint2*)(xnb + (size_t)(m + k - 2) * DIMC))[t];
        acc[0] += bf2f((unsigned short)(rv.x & 0xffff)) * wgt[0][k];
        acc[1] += bf2f((unsigned short)(rv.x >> 16))    * wgt[1][k];
        acc[2] += bf2f((unsigned short)(rv.y & 0xffff)) * wgt[2][k];
        acc[3] += bf2f((unsigned short)(rv.y >> 16))    * wgt[3][k];
    }
    uint2 o;
    o.x = (unsigned)f2bf(acc[0]) | ((unsigned)f2bf(acc[1]) << 16);
    o.y = (unsigned)f2bf(acc[2]) | ((unsigned)f2bf(acc[3]) << 16);
    ((uint2*)(xc + (size_t)m * DIMC))[t] = o;
}

// ---------------- chunked parallel scan ----------------
__global__ __launch_bounds__(256) void k_scan_a(const unsigned short* __restrict__ xnb,
                                                const float* __restrict__ alpha,
                                                const float* __restrict__ beta,
                                                float* __restrict__ F) {
    int blk = blockIdx.x;        // b*NCHUNK + k
    int b = blk >> 5, k = blk & (NCHUNK - 1);
    int c = threadIdx.x;
    float a = alpha[c], bt = beta[c];
    const unsigned short* p = xnb + ((size_t)(b * LL + k * LC)) * DIMC + c;
    float h = 0.0f;
    for (int l = 0; l < LC; ++l) h = a * h + bt * bf2f(p[(size_t)l * DIMC]);
    F[(size_t)blk * ACTC + c] = h;
}
__global__ __launch_bounds__(256) void k_scan_b(const float* __restrict__ alpha,
                                                const float* __restrict__ F,
                                                float* __restrict__ Cv) {
    int b = blockIdx.x;
    int c = threadIdx.x;
    float a = alpha[c];
    float aL = a;
#pragma unroll
    for (int i = 0; i < 6; ++i) aL *= aL;   // a^64
    float T = 0.0f;
    for (int k = 0; k < NCHUNK; ++k) {
        size_t idx = ((size_t)b * NCHUNK + k) * ACTC + c;
        Cv[idx] = T;
        T = F[idx] + aL * T;
    }
}
__global__ __launch_bounds__(256) void k_scan_c(const unsigned short* __restrict__ xnb,
                                                const float* __restrict__ alpha,
                                                const float* __restrict__ beta,
                                                const float* __restrict__ Cv,
                                                unsigned short* __restrict__ hs) {
    int blk = blockIdx.x;
    int b = blk >> 5, k = blk & (NCHUNK - 1);
    int c = threadIdx.x;
    float a = alpha[c], bt = beta[c];
    const unsigned short* p = xnb + ((size_t)(b * LL + k * LC)) * DIMC + c;
    unsigned short*       q = hs  + ((size_t)(b * LL + k * LC)) * ACTC + c;
    float h = Cv[(size_t)blk * ACTC + c];
    for (int l = 0; l < LC; ++l) {
        h = a * h + bt * bf2f(p[(size_t)l * DIMC]);
        q[(size_t)l * ACTC] = f2bf(h);
    }
}

// ---------------- MFMA GEMM, C = A(MxK) * B^T(NxK), fused epilogues ----------------
// XOR-swizzled LDS staging; residual adds read COALESCED in the store phase
// (acc-layout scatter reads were 64-128 scalar loads/lane — R6 bottleneck).
// NOTE: MODE1 must stay at launch_bounds(256,2) — (256,3) caps VGPRs at ~85 and
// spills the 2x 4x4 f32x4 accumulators to scratch (R5: WRITE_SIZE 32->121MB, 2.2x slower).
#define TM 128
#define TN 128
#define BK 64

#define GLOAD_LDS(gp, lp) \
    __builtin_amdgcn_global_load_lds((const __attribute__((address_space(1))) unsigned int*)(gp), \
                                     (__attribute__((address_space(3))) unsigned int*)(lp), 16, 0, 0)

template<int MODE>
__global__ __launch_bounds__(256, (MODE == 1) ? 2 : 4) void k_gemm(
        const unsigned short* __restrict__ A,
        const unsigned short* __restrict__ B0,
        const unsigned short* __restrict__ B1,
        const float* __restrict__ bias0,
        const float* __restrict__ bias1,
        const unsigned short* __restrict__ add0,
        const unsigned short* __restrict__ add1,
        const float* __restrict__ addf,
        float* __restrict__ outf,
        unsigned short* __restrict__ outb,
        int M, int N, int K)
{
    constexpr int LDSB = (MODE == 1) ? 49152 : 32768;
    __shared__ __align__(16) char lds[LDSB];
    unsigned short* sA  = (unsigned short*)lds;
    unsigned short* sB0 = (unsigned short*)(lds + 16384);
    unsigned short* sB1 = (unsigned short*)(lds + 32768);

    // XCD-aware remap: bid&7 selects M-partition (XCD proxy), column varies
    // fastest within an XCD so the A-tile stays hot in that XCD's L2.
    int nx = gridDim.x;
    int bid = blockIdx.y * nx + blockIdx.x;
    int xcd = bid & 7, s = bid >> 3;
    int colt = s % nx, rowgrp = s / nx;
    int m0 = (rowgrp * 8 + xcd) * TM;
    int n0 = colt * TN;

    int t = threadIdx.x;
    int w = t >> 6, lane = t & 63;
    int wm = (w >> 1) * 64, wn = (w & 1) * 64;
    int quad = lane >> 4, lm = lane & 15;
    int lm7 = lm & 7;

    f32x4 zero = {0.f, 0.f, 0.f, 0.f};
    f32x4 acc0[4][4];
    f32x4 acc1[(MODE == 1) ? 4 : 1][(MODE == 1) ? 4 : 1];
#pragma unroll
    for (int i = 0; i < 4; ++i)
#pragma unroll
        for (int j = 0; j < 4; ++j) acc0[i][j] = zero;
    if constexpr (MODE == 1) {
#pragma unroll
        for (int i = 0; i < 4; ++i)
#pragma unroll
            for (int j = 0; j < 4; ++j) acc1[i][j] = zero;
    }

    for (int k0 = 0; k0 < K; k0 += BK) {
        __syncthreads();
#pragma unroll
        for (int c = 0; c < 4; ++c) {
            int i = t + c * 256;
            int r = i >> 3;
            int sc = ((i & 7) ^ (r & 7)) << 3;   // swizzled source k-group
            GLOAD_LDS(A  + (size_t)(m0 + r) * K + k0 + sc, sA  + i * 8);
            GLOAD_LDS(B0 + (size_t)(n0 + r) * K + k0 + sc, sB0 + i * 8);
            if constexpr (MODE == 1)
                GLOAD_LDS(B1 + (size_t)(n0 + r) * K + k0 + sc, sB1 + i * 8);
        }
        __syncthreads();

#pragma unroll
        for (int ks = 0; ks < BK; ks += 32) {
            int cgb = ks >> 3;   // 0 or 4
            bf16x8 af[4], b0f[4];
#pragma unroll
            for (int i = 0; i < 4; ++i) {
                int sg = ((cgb + quad) ^ lm7) << 3;
                af[i]  = *(const bf16x8*)(sA  + (wm + i * 16 + lm) * BK + sg);
                b0f[i] = *(const bf16x8*)(sB0 + (wn + i * 16 + lm) * BK + sg);
            }
            if constexpr (MODE == 1) {
                bf16x8 b1f[4];
#pragma unroll
                for (int i = 0; i < 4; ++i)
                    b1f[i] = *(const bf16x8*)(sB1 + (wn + i * 16 + lm) * BK + (((cgb + quad) ^ lm7) << 3));
#pragma unroll
                for (int mi = 0; mi < 4; ++mi)
#pragma unroll
                    for (int ni = 0; ni < 4; ++ni) {
                        acc0[mi][ni] = __builtin_amdgcn_mfma_f32_16x16x32_bf16(af[mi], b0f[ni], acc0[mi][ni], 0, 0, 0);
                        acc1[mi][ni] = __builtin_amdgcn_mfma_f32_16x16x32_bf16(af[mi], b1f[ni], acc1[mi][ni], 0, 0, 0);
                    }
            } else {
#pragma unroll
                for (int mi = 0; mi < 4; ++mi)
#pragma unroll
                    for (int ni = 0; ni < 4; ++ni)
                        acc0[mi][ni] = __builtin_amdgcn_mfma_f32_16x16x32_bf16(af[mi], b0f[ni], acc0[mi][ni], 0, 0, 0);
            }
        }
    }

    // -------- epilogue: acc-layout math -> LDS pack -> coalesced store + coalesced adds --------
    __syncthreads();
    if constexpr (MODE == 3) {
        // fp32: two 64-row halves within 32 KB LDS; adds done coalesced at store
        float* sO = (float*)lds;
#pragma unroll
        for (int half = 0; half < 2; ++half) {
            if (wm == half * 64) {
#pragma unroll
                for (int mi = 0; mi < 4; ++mi) {
#pragma unroll
                    for (int ni = 0; ni < 4; ++ni) {
                        int nl = wn + ni * 16 + lm;
                        float bn = bias0[n0 + nl];
#pragma unroll
                        for (int j = 0; j < 4; ++j) {
                            int mloc = mi * 16 + quad * 4 + j;   // 0..63
                            sO[mloc * TN + nl] = acc0[mi][ni][j] + bn;
                        }
                    }
                }
            }
            __syncthreads();
#pragma unroll
            for (int c = 0; c < 8; ++c) {
                int i = t + c * 256;
                int r = i >> 5, c4 = (i & 31) << 2;
                int m = m0 + half * 64 + r, n = n0 + c4;
                float4 v  = *(float4*)(sO + r * TN + c4);
                uint2  ab = *(const uint2*)(add0 + (size_t)m * N + n);
                float4 xf = *(const float4*)(addf + (size_t)m * N + n);
                float4 o;
                o.x = v.x + bf2f((unsigned short)(ab.x & 0xffff)) + xf.x;
                o.y = v.y + bf2f((unsigned short)(ab.x >> 16))    + xf.y;
                o.z = v.z + bf2f((unsigned short)(ab.y & 0xffff)) + xf.z;
                o.w = v.w + bf2f((unsigned short)(ab.y >> 16))    + xf.w;
                *(float4*)(outf + (size_t)m * N + n) = o;
            }
            __syncthreads();
        }
    } else {
        unsigned short* sO = (unsigned short*)lds;
#pragma unroll
        for (int mi = 0; mi < 4; ++mi) {
#pragma unroll
            for (int ni = 0; ni < 4; ++ni) {
                int nl = wn + ni * 16 + lm;
                int n  = n0 + nl;
                float bn = bias0[n];
                float bn1 = (MODE == 1) ? bias1[n] : 0.0f;
#pragma unroll
                for (int j = 0; j < 4; ++j) {
                    int ml = wm + mi * 16 + quad * 4 + j;
                    float v = acc0[mi][ni][j];
                    float r;
                    if constexpr (MODE == 0) {
                        r = v + bn;                       // residual added at store
                    } else if constexpr (MODE == 1) {
                        float u1 = v + bn;
                        float u2 = acc1[mi][ni][j] + bn1;
                        r = fast_sigmoid(u1) * fast_tanh(u2);   // y1 added at store
                    } else { // MODE 2
                        float u = v + bn;
                        r = 0.5f * u * (1.0f + erff(u * 0.70710678118654752f));
                    }
                    sO[ml * TN + nl] = f2bf(r);
                }
            }
        }
        __syncthreads();
#pragma unroll
        for (int c = 0; c < 8; ++c) {
            int i = t + c * 256;
            int r = i >> 4, c8 = (i & 15) << 3;
            int m = m0 + r, n = n0 + c8;
            uint4 g = *(uint4*)(sO + r * TN + c8);
            if constexpr (MODE == 2) {
                *(uint4*)(outb + (size_t)m * N + n) = g;
            } else {
                uint4 av;
                if constexpr (MODE == 0) {
                    av = (n0 < ACTC) ? *(const uint4*)(add0 + (size_t)m * ACTC + n)
                                     : *(const uint4*)(add1 + (size_t)m * DIMC + n);
                } else {
                    av = *(const uint4*)(add0 + (size_t)m * N + n);
                }
                unsigned* gp = (unsigned*)&g;
                unsigned* ap = (unsigned*)&av;
                uint4 o;
                unsigned* op = (unsigned*)&o;
#pragma unroll
                for (int q = 0; q < 4; ++q) {
                    float lo = bf2f((unsigned short)(gp[q] & 0xffff)) + bf2f((unsigned short)(ap[q] & 0xffff));
                    float hi = bf2f((unsigned short)(gp[q] >> 16))    + bf2f((unsigned short)(ap[q] >> 16));
                    op[q] = (unsigned)f2bf(lo) | ((unsigned)f2bf(hi) << 16);
                }
                *(uint4*)(outb + (size_t)m * N + n) = o;
            }
        }
    }
}

extern "C" void kernel_launch(void* const* d_in, const int* in_sizes, int n_in,
                              void* d_out, int out_size, void* d_ws, size_t ws_size,
                              hipStream_t stream) {
    (void)in_sizes; (void)n_in; (void)out_size; (void)ws_size;
    const float* x      = (const float*)d_in[0];
    const float* norm_w = (const float*)d_in[1];
    const float* dw_w   = (const float*)d_in[2];
    const float* dw_b   = (const float*)d_in[3];
    const float* pw_w   = (const float*)d_in[4];
    const float* pw_b   = (const float*)d_in[5];
    const float* alpha  = (const float*)d_in[6];
    const float* beta   = (const float*)d_in[7];
    const float* W1_w   = (const float*)d_in[8];
    const float* W1_b   = (const float*)d_in[9];
    const float* W2_w   = (const float*)d_in[10];
    const float* W2_b   = (const float*)d_in[11];
    const float* down_w = (const float*)d_in[12];
    const float* down_b = (const float*)d_in[13];
    const float* up_w   = (const float*)d_in[14];
    const float* up_b   = (const float*)d_in[15];

    char* ws = (char*)d_ws;
    unsigned short* xnb  = (unsigned short*)(ws);
    unsigned short* xc   = (unsigned short*)(ws + 33554432ull);
    unsigned short* hs   = (unsigned short*)(ws + 67108864ull);
    unsigned short* y1b  = (unsigned short*)(ws + 75497472ull);
    unsigned short* y2b  = (unsigned short*)(ws + 109051904ull);
    unsigned short* gact = (unsigned short*)(ws + 142606336ull);
    unsigned short* wpw  = (unsigned short*)(ws + 150994944ull);
    unsigned short* w1b  = wpw + 1048576;
    unsigned short* w2b  = w1b + 1048576;
    unsigned short* wdn  = w2b + 1048576;
    unsigned short* wup  = wdn + 262144;
    float*          Fb   = (float*)(ws + 159383552ull);
    float*          Cb   = (float*)(ws + 159383552ull + 262144ull);

    k_convert5<<<14336, 256, 0, stream>>>(pw_w, W1_w, W2_w, down_w, up_w,
                                          wpw, w1b, w2b, wdn, wup);

    k_rmsnorm<<<MROWS, 256, 0, stream>>>(x, norm_w, xnb);
    k_dwconv <<<MROWS, 256, 0, stream>>>(xnb, dw_w, dw_b, xc);

    k_scan_a<<<BB * NCHUNK, ACTC, 0, stream>>>(xnb, alpha, beta, Fb);
    k_scan_b<<<BB, ACTC, 0, stream>>>(alpha, Fb, Cb);
    k_scan_c<<<BB * NCHUNK, ACTC, 0, stream>>>(xnb, alpha, beta, Cb, hs);

    dim3 g1(DIMC / TN, MROWS / TM);
    dim3 g2(HIDC / TN, MROWS / TM);
    k_gemm<0><<<g1, 256, 0, stream>>>(xc, wpw, nullptr, pw_b, nullptr, hs, xnb, nullptr, nullptr, y1b, MROWS, DIMC, DIMC);
    k_gemm<1><<<g1, 256, 0, stream>>>(y1b, w1b, w2b, W1_b, W2_b, y1b, nullptr, nullptr, nullptr, y2b, MROWS, DIMC, DIMC);
    k_gemm<2><<<g2, 256, 0, stream>>>(y2b, wdn, nullptr, down_b, nullptr, nullptr, nullptr, nullptr, nullptr, gact, MROWS, HIDC, DIMC);
    k_gemm<3><<<g1, 256, 0, stream>>>(gact, wup, nullptr, up_b, nullptr, y2b, nullptr, x, (float*)d_out, nullptr, MROWS, DIMC, HIDC);
}